// Round 18
// baseline (194.814 us; speedup 1.0000x reference)
//
#include <hip/hip_runtime.h>
#include <hip/hip_bf16.h>
#include <hip/hip_fp16.h>

// SplineCNN forward, MI355X round 18.
// R17 -> R18: edge blocks widened to 512 threads (8 waves x 64 edges), W
// staged ONCE per 512 edges. Unlike R16's failed 2-round-per-wave version,
// per-wave register state is unchanged (4 tiles/wave) - we add waves, not
// serial rounds. Halves block count, staging traffic, barriers. Root role
// now 128 nodes/block. Everything else identical to R17.

typedef __attribute__((ext_vector_type(8))) _Float16 f16x8;
typedef __attribute__((ext_vector_type(4))) _Float16 f16x4;
typedef __attribute__((ext_vector_type(4))) float f32x4;

constexpr int NN = 50000;       // nodes
constexpr int EE = 800000;      // edges
constexpr int BCHUNK = 512;     // edges per edge-block (8 waves x 64)
constexpr int EB = EE / 256;    // 3125 prep/scatter blocks
static_assert(EE % 256 == 0, "prep grid assumes exact divisibility");
constexpr int ELIST_LEN = EE + 16 * BCHUNK;
constexpr int NBLK_EDGE = ELIST_LEN / BCHUNK;   // 1579
constexpr int RT_BLK = (NN + 127) / 128;        // 391 root-GEMM blocks

// ------------------------------------------------- detect + workspace init
__global__ __launch_bounds__(256) void detect_init(
    const long long* __restrict__ eidx, int* __restrict__ flag,
    int* __restrict__ degi) {
  if (blockIdx.x == 0 && threadIdx.x < 64) {
    long long v = eidx[threadIdx.x];
    bool ok = (v >= 0) && (v < (long long)NN);
    unsigned long long m = __ballot(ok);
    if (threadIdx.x == 0) flag[0] = (m == ~0ull) ? 1 : 0;
  }
  const int i = blockIdx.x * 256 + threadIdx.x;
  if (i < NN) degi[i] = 0;
}

// ------------------------------------------------- prep + one-shot converts
constexpr int F2H_LEN8 = NN * 32 / 8;                 // 200000
constexpr int F2H_BLK = (F2H_LEN8 + 255) / 256;       // 782
constexpr int CW32_BLK = 4 * 16;                      // 64
constexpr int CW64_BLK = 8 * 16;                      // 128
constexpr int CFW_BLK = (64 * 160) / 256;             // 40
constexpr int CRT0_BLK = (64 * 32) / 256;             // 8
constexpr int CRT1_BLK = (64 * 64) / 256;             // 16
constexpr int CONV_BLK = F2H_BLK + CW32_BLK + CW64_BLK + CFW_BLK + CRT0_BLK + CRT1_BLK;

template <int IN>
__device__ __forceinline__ void conv_w_body(
    const float* __restrict__ w, _Float16* __restrict__ wcell, int c, int o) {
  constexpr int K = 4 * IN;
  constexpr int RS = K * 2;
  constexpr int OPR = K / 8;
  const int bx = c & 3, by = c >> 2;
  const int n = o / OPR;
  const int k0 = (o - n * OPR) * 8;
  const int ks = k0 >> 5;
  const int g2 = (k0 & 31) >> 3;
  const int s = (IN == 64) ? (ks & 3) : ks;
  const int i0 = ((IN == 64) ? (ks >> 2) * 32 : 0) + g2 * 8;
  const int kk = (bx + (s & 1)) + 5 * (by + (s >> 1));
  const float* wp = w + ((size_t)kk * IN + i0) * 64 + n;
  f16x8 v;
#pragma unroll
  for (int j = 0; j < 8; ++j) v[j] = (_Float16)wp[(size_t)j * 64];
  const int byte = n * RS + ((k0 * 2) ^ ((n & 15) << 4));
  *reinterpret_cast<f16x8*>(
      reinterpret_cast<char*>(wcell) + (size_t)c * (RS * 64) + byte) = v;
}

__global__ __launch_bounds__(256) void prep_conv(
    const void* __restrict__ eidx, const float* __restrict__ attr,
    const int* __restrict__ flag,
    int* __restrict__ src, int* __restrict__ dst, int* __restrict__ rankE,
    int* __restrict__ degi, int* __restrict__ bhT,
    const float* __restrict__ x0, const float* __restrict__ w0,
    const float* __restrict__ w1, const float* __restrict__ fw,
    const float* __restrict__ root0, const float* __restrict__ root1,
    _Float16* __restrict__ xh0, _Float16* __restrict__ wc0,
    _Float16* __restrict__ wc1, _Float16* __restrict__ fwT,
    _Float16* __restrict__ rt0T, _Float16* __restrict__ rt1T) {
  __shared__ int wc[4][16];
  const int tid = threadIdx.x;
  if (blockIdx.x < EB) {
    const int e = blockIdx.x * 256 + tid;
    int s, d;
    if (flag[0]) {
      s = (int)((const long long*)eidx)[e];
      d = (int)((const long long*)eidx)[EE + e];
    } else {
      s = ((const int*)eidx)[e];
      d = ((const int*)eidx)[EE + e];
    }
    src[e] = s;
    dst[e] = d;
    rankE[e] = atomicAdd(&degi[d], 1);   // rank within dst segment
    const float v0 = attr[2 * e] * 4.0f, v1 = attr[2 * e + 1] * 4.0f;
    const int bx = min(max((int)floorf(v0), 0), 3);
    const int by = min(max((int)floorf(v1), 0), 3);
    const int c = bx + 4 * by;
    const int wave = tid >> 6, lane = tid & 63;
#pragma unroll
    for (int k = 0; k < 16; ++k) {
      unsigned long long mm = __ballot(c == k);
      if (lane == k) wc[wave][k] = __popcll(mm);
    }
    __syncthreads();
    if (tid < 16)
      bhT[tid * EB + blockIdx.x] = wc[0][tid] + wc[1][tid] + wc[2][tid] + wc[3][tid];
    return;
  }
  const int b = blockIdx.x - EB;
  if (b < F2H_BLK) {
    const int i = b * 256 + tid;
    if (i >= F2H_LEN8) return;
    const float4 a = reinterpret_cast<const float4*>(x0)[i * 2];
    const float4 bb = reinterpret_cast<const float4*>(x0)[i * 2 + 1];
    f16x8 v = {(_Float16)a.x, (_Float16)a.y, (_Float16)a.z, (_Float16)a.w,
               (_Float16)bb.x, (_Float16)bb.y, (_Float16)bb.z, (_Float16)bb.w};
    reinterpret_cast<f16x8*>(xh0)[i] = v;
  } else if (b < F2H_BLK + CW32_BLK) {
    const int r = b - F2H_BLK;
    conv_w_body<32>(w0, wc0, r >> 2, (r & 3) * 256 + tid);
  } else if (b < F2H_BLK + CW32_BLK + CW64_BLK) {
    const int r = b - F2H_BLK - CW32_BLK;
    conv_w_body<64>(w1, wc1, r >> 3, (r & 7) * 256 + tid);
  } else if (b < F2H_BLK + CW32_BLK + CW64_BLK + CFW_BLK) {
    const int i = (b - F2H_BLK - CW32_BLK - CW64_BLK) * 256 + tid;  // < 10240
    const int n = i / 160, k = i - n * 160;
    fwT[i] = (_Float16)fw[k * 64 + n];
  } else if (b < F2H_BLK + CW32_BLK + CW64_BLK + CFW_BLK + CRT0_BLK) {
    const int i = (b - F2H_BLK - CW32_BLK - CW64_BLK - CFW_BLK) * 256 + tid;
    const int n = i / 32, k = i - n * 32;   // i < 2048
    rt0T[i] = (_Float16)root0[k * 64 + n];
  } else {
    const int i = (b - F2H_BLK - CW32_BLK - CW64_BLK - CFW_BLK - CRT0_BLK) * 256 + tid;
    const int n = i / 64, k = i - n * 64;   // i < 4096
    rt1T[i] = (_Float16)root1[k * 64 + n];
  }
}

// --------------------------------------------------------------- fused scans
// Cell segments padded to BCHUNK multiples; chunkcell per 512-edge chunk.
__global__ __launch_bounds__(1024) void scan_fused(
    const int* __restrict__ bhT, int* __restrict__ blkbaseT,
    int* __restrict__ chunkcell, int2* __restrict__ posrcS,
    const int* __restrict__ degi, int* __restrict__ dstbase) {
  const int wave = threadIdx.x >> 6, lane = threadIdx.x & 63;
  if (blockIdx.x == 0) {
    constexpr int CH = (EB + 63) / 64;   // 49
    __shared__ int ofs_s[16];
    __shared__ int tot_s[16];
    int v[CH];
#pragma unroll
    for (int ch = 0; ch < CH; ++ch) {
      const int b = ch * 64 + lane;
      v[ch] = (b < EB) ? bhT[wave * EB + b] : 0;
    }
    {
      int sum = 0;
#pragma unroll
      for (int ch = 0; ch < CH; ++ch) sum += v[ch];
#pragma unroll
      for (int off = 32; off > 0; off >>= 1) sum += __shfl_down(sum, off);
      if (lane == 0) tot_s[wave] = sum;
    }
    __syncthreads();
    if (threadIdx.x == 0) {
      int t = 0;
      for (int c = 0; c < 16; ++c) {
        ofs_s[c] = t;
        t += ((tot_s[c] + BCHUNK - 1) / BCHUNK) * BCHUNK;
      }
    }
    __syncthreads();
    {  // 512-chunk -> cell map; padding chunks get -1
      const int nch = (tot_s[wave] + BCHUNK - 1) / BCHUNK;
      const int cb = ofs_s[wave] / BCHUNK;
      for (int i = lane; i < nch; i += 64) chunkcell[cb + i] = wave;
      if (wave == 15) {
        const int totch = cb + nch;
        for (int i = totch + lane; i < NBLK_EDGE; i += 64) chunkcell[i] = -1;
      }
    }
    {  // pad sentinels for this cell's segment
      const int startp = ofs_s[wave] + tot_s[wave];
      const int endp = ofs_s[wave] + ((tot_s[wave] + BCHUNK - 1) / BCHUNK) * BCHUNK;
      for (int p = startp + lane; p < endp; p += 64) posrcS[p] = make_int2(-1, 0);
    }
    int running = ofs_s[wave];
#pragma unroll
    for (int ch = 0; ch < CH; ++ch) {
      int inc = v[ch];
#pragma unroll
      for (int off = 1; off < 64; off <<= 1) {
        int n = __shfl_up(inc, off);
        if (lane >= off) inc += n;
      }
      const int b = ch * 64 + lane;
      if (b < EB) blkbaseT[wave * EB + b] = running + inc - v[ch];
      running += __shfl(inc, 63);
    }
  } else {
    constexpr int SEG = NN / 16;          // 3125
    constexpr int CH = (SEG + 63) / 64;   // 49
    __shared__ int wofs[16];
    const int nbase = wave * SEG;
    int v[CH];
#pragma unroll
    for (int ch = 0; ch < CH; ++ch) {
      const int i = ch * 64 + lane;
      v[ch] = (i < SEG) ? degi[nbase + i] : 0;
    }
    {
      int sum = 0;
#pragma unroll
      for (int ch = 0; ch < CH; ++ch) sum += v[ch];
#pragma unroll
      for (int off = 32; off > 0; off >>= 1) sum += __shfl_down(sum, off);
      if (lane == 0) wofs[wave] = sum;
    }
    __syncthreads();
    if (threadIdx.x == 0) {
      int t = 0;
      for (int w2 = 0; w2 < 16; ++w2) { int tv = wofs[w2]; wofs[w2] = t; t += tv; }
    }
    __syncthreads();
    int running = wofs[wave];
#pragma unroll
    for (int ch = 0; ch < CH; ++ch) {
      int inc = v[ch];
#pragma unroll
      for (int off = 1; off < 64; off <<= 1) {
        int n = __shfl_up(inc, off);
        if (lane >= off) inc += n;
      }
      const int i = ch * 64 + lane;
      if (i < SEG) dstbase[nbase + i] = running + inc - v[ch];
      running += __shfl(inc, 63);
    }
  }
}

// Deterministic cell-sorted scatter; basis from attr; pos = dstbase + rankE.
__global__ __launch_bounds__(256) void scatter_edges(
    const float* __restrict__ attr, const int* __restrict__ blkbaseT,
    const int* __restrict__ srcArr, const int* __restrict__ dstArr,
    const int* __restrict__ rankE, const int* __restrict__ dstbase,
    int2* __restrict__ posrcS, f16x4* __restrict__ basS) {
  __shared__ int wc[4][16];
  __shared__ int bs[4][16];
  const int tid = threadIdx.x;
  const int e = blockIdx.x * 256 + tid;
  const float v0 = attr[2 * e] * 4.0f, v1 = attr[2 * e + 1] * 4.0f;
  const float fl0 = floorf(v0), fl1 = floorf(v1);
  const float fr0 = v0 - fl0, fr1 = v1 - fl1;
  const int bx = min(max((int)fl0, 0), 3);
  const int by = min(max((int)fl1, 0), 3);
  const int c = bx + 4 * by;
  const f16x4 bq = {(_Float16)((1.0f - fr0) * (1.0f - fr1)),
                    (_Float16)(fr0 * (1.0f - fr1)),
                    (_Float16)((1.0f - fr0) * fr1),
                    (_Float16)(fr0 * fr1)};
  const int wave = tid >> 6, lane = tid & 63;
  int rank = 0;
#pragma unroll
  for (int k = 0; k < 16; ++k) {
    unsigned long long mm = __ballot(c == k);
    if (k == c) rank = __popcll(mm & ((1ull << lane) - 1ull));
    if (lane == k) wc[wave][k] = __popcll(mm);
  }
  const int mypos = dstbase[dstArr[e]] + rankE[e];
  __syncthreads();
  if (tid < 16) {
    int running = blkbaseT[tid * EB + blockIdx.x];
#pragma unroll
    for (int w = 0; w < 4; ++w) { bs[w][tid] = running; running += wc[w][tid]; }
  }
  __syncthreads();
  const int p = bs[wave][c] + rank;
  posrcS[p] = make_int2(srcArr[e], mypos);
  basS[p] = bq;
}

// ------------------------------------------------- edge msg + root GEMM
// 512-thread blocks: edge role = 8 waves x 64 edges (4 tiles each), W staged
// once; per-wave structure identical to R17. Root role = 128 nodes/block.
template <int IN, bool TWOPASS>
__global__ __launch_bounds__(512) void edge_root(
    const _Float16* __restrict__ xh, const _Float16* __restrict__ wcell,
    const int* __restrict__ chunkcell,
    const int2* __restrict__ posrcS, const f16x4* __restrict__ basS,
    const _Float16* __restrict__ rootT, const float* __restrict__ bias,
    _Float16* __restrict__ rth,
    unsigned char* __restrict__ msg, float* __restrict__ agg) {
  constexpr int K = 4 * IN;
  constexpr int KSTEPS = K / 32;
  constexpr int RS = K * 2;            // LDS row stride bytes
  constexpr int OPR = K / 8;           // 16B chunks per row
  constexpr int TILES = 4;             // per wave
  constexpr int NCH = (IN == 64) ? 2 : 1;
  __shared__ f16x8 Wt[64 * OPR];
  const int tid = threadIdx.x;
  const int lane = tid & 63;
  const int wave = tid >> 6;           // 0..7
  const int g = lane >> 4, m = lane & 15;
  if (blockIdx.x >= NBLK_EDGE) {       // ---- root GEMM role ----
    constexpr int KS = IN / 32;
    const int base = (blockIdx.x - NBLK_EDGE) * 128 + wave * 16;
    if (base >= NN) return;
    f16x8 bf[KS][4];
#pragma unroll
    for (int ks = 0; ks < KS; ++ks)
#pragma unroll
      for (int nt = 0; nt < 4; ++nt)
        bf[ks][nt] = *reinterpret_cast<const f16x8*>(
            rootT + (size_t)(nt * 16 + m) * IN + ks * 32 + g * 8);
    const int row = base + m;
    f16x8 a[KS];
#pragma unroll
    for (int ks = 0; ks < KS; ++ks)
      a[ks] = *reinterpret_cast<const f16x8*>(xh + (size_t)row * IN + ks * 32 + g * 8);
    f32x4 acc[4];
#pragma unroll
    for (int nt = 0; nt < 4; ++nt) {
      const float fv = bias[nt * 16 + m];
      acc[nt] = (f32x4){fv, fv, fv, fv};
    }
#pragma unroll
    for (int ks = 0; ks < KS; ++ks)
#pragma unroll
      for (int nt = 0; nt < 4; ++nt)
        acc[nt] = __builtin_amdgcn_mfma_f32_16x16x32_f16(a[ks], bf[ks][nt], acc[nt], 0, 0, 0);
#pragma unroll
    for (int r = 0; r < 4; ++r) {
      const int node = base + g * 4 + r;
      f16x4 pv = {(_Float16)acc[0][r], (_Float16)acc[1][r],
                  (_Float16)acc[2][r], (_Float16)acc[3][r]};
      *reinterpret_cast<f16x4*>(rth + (size_t)node * 64 + m * 4) = pv;
    }
    return;
  }
  // ---- edge transform role ----
  const int c = chunkcell[blockIdx.x];
  if (c < 0) return;                   // fully-padded chunk
  const int base = blockIdx.x * BCHUNK;
  const int wbase = base + wave * 64;  // this wave's 64 edges
  int2 sp_t[TILES];
  f16x4 bas_t[TILES];
#pragma unroll
  for (int t = 0; t < TILES; ++t) sp_t[t] = posrcS[wbase + t * 16 + m];
#pragma unroll
  for (int t = 0; t < TILES; ++t) bas_t[t] = basS[wbase + t * 16 + m];
  {
    const f16x8* gw = reinterpret_cast<const f16x8*>(wcell) + (size_t)c * (64 * OPR);
    for (int o = tid; o < 64 * OPR; o += 512) Wt[o] = gw[o];
  }
  __syncthreads();
  f16x8 xc[TILES][NCH];
#pragma unroll
  for (int t = 0; t < TILES; ++t) {
    const int row = (sp_t[t].x >= 0) ? sp_t[t].x : 0;
    const f16x8* xr = reinterpret_cast<const f16x8*>(xh + (size_t)row * IN);
    xc[t][0] = xr[g];
    if constexpr (IN == 64) xc[t][1] = xr[4 + g];
  }
  f32x4 acc[TILES][4];
#pragma unroll
  for (int t = 0; t < TILES; ++t)
#pragma unroll
    for (int nt = 0; nt < 4; ++nt) acc[t][nt] = (f32x4){0.f, 0.f, 0.f, 0.f};
#pragma unroll
  for (int ks = 0; ks < KSTEPS; ++ks) {
    const int s = (IN == 64) ? (ks & 3) : ks;
    f16x8 a[TILES];
#pragma unroll
    for (int t = 0; t < TILES; ++t) {
      const f16x8 xin = (IN == 64 && (ks >> 2)) ? xc[t][1] : xc[t][0];
      a[t] = xin * bas_t[t][s];
    }
#pragma unroll
    for (int nt = 0; nt < 4; ++nt) {
      const int n = nt * 16 + m;
      const int byte = n * RS + (((ks * 64) + g * 16) ^ ((n & 15) << 4));
      const f16x8 bfrag = Wt[byte >> 4];   // ONE LDS read -> 4 MFMAs
#pragma unroll
      for (int t = 0; t < TILES; ++t)
        acc[t][nt] = __builtin_amdgcn_mfma_f32_16x16x32_f16(a[t], bfrag, acc[t][nt], 0, 0, 0);
    }
  }
#pragma unroll
  for (int t = 0; t < TILES; ++t) {
#pragma unroll
    for (int r = 0; r < 4; ++r) {
      const int m2 = g * 4 + r;
      const int er = __shfl(sp_t[t].x, m2);
      const int pr = __shfl(sp_t[t].y, m2);
      if (er >= 0) {
        if constexpr (TWOPASS) {
          unsigned int p8 = __builtin_amdgcn_cvt_pk_fp8_f32(acc[t][0][r], acc[t][1][r], 0u, false);
          p8 = __builtin_amdgcn_cvt_pk_fp8_f32(acc[t][2][r], acc[t][3][r], p8, true);
          *reinterpret_cast<unsigned int*>(msg + (size_t)pr * 64 + m * 4) = p8;
        } else {
          float* ap = agg + (size_t)pr * 64 + m;
#pragma unroll
          for (int nt = 0; nt < 4; ++nt) atomicAdd(ap + nt * 16, acc[t][nt][r]);
        }
      }
    }
  }
}

// ------------------------------------------------- pass2 helpers
__device__ __forceinline__ float seg_reduce_fp8(
    const unsigned char* __restrict__ msg, int b0, int dg, int q, int m) {
  const unsigned int* mp =
      reinterpret_cast<const unsigned int*>(msg + (size_t)b0 * 64 + m * 4);
  float a0 = 0.f, a1 = 0.f, a2 = 0.f, a3 = 0.f;
  const int nfull = dg & ~15;
  int j0 = 0;
  for (; j0 < nfull; j0 += 16) {
    const unsigned int* bp = mp + (size_t)j0 * 16;
#pragma unroll
    for (int u = 0; u < 4; ++u) {
      const unsigned int pw = bp[(size_t)(u * 4 + q) * 16];
      const auto lo = __builtin_amdgcn_cvt_pk_f32_fp8(pw, false);
      const auto hi = __builtin_amdgcn_cvt_pk_f32_fp8(pw, true);
      a0 += lo[0]; a1 += lo[1]; a2 += hi[0]; a3 += hi[1];
    }
  }
  if (j0 < dg) {
#pragma unroll
    for (int u = 0; u < 4; ++u) {
      const int jj = j0 + u * 4 + q;
      const int jc = min(jj, dg - 1);
      const unsigned int pw = mp[(size_t)jc * 16];
      const auto lo = __builtin_amdgcn_cvt_pk_f32_fp8(pw, false);
      const auto hi = __builtin_amdgcn_cvt_pk_f32_fp8(pw, true);
      const float wv = (jj < dg) ? 1.0f : 0.0f;
      a0 = fmaf(wv, lo[0], a0);
      a1 = fmaf(wv, lo[1], a1);
      a2 = fmaf(wv, hi[0], a2);
      a3 = fmaf(wv, hi[1], a3);
    }
  }
  a0 += __shfl_xor(a0, 16); a0 += __shfl_xor(a0, 32);
  a1 += __shfl_xor(a1, 16); a1 += __shfl_xor(a1, 32);
  a2 += __shfl_xor(a2, 16); a2 += __shfl_xor(a2, 32);
  a3 += __shfl_xor(a3, 16); a3 += __shfl_xor(a3, 32);
  return (q == 0) ? a0 : (q == 1) ? a1 : (q == 2) ? a2 : a3;
}

// --------------------------------------------------------------- pass2 (L0)
__global__ __launch_bounds__(256) void pass2_kernel(
    const unsigned char* __restrict__ msg, const int* __restrict__ dstbase,
    const int* __restrict__ degi, const _Float16* __restrict__ rth,
    _Float16* __restrict__ xh_out) {
  const int wave = threadIdx.x >> 6, lane = threadIdx.x & 63;
  const int n = blockIdx.x * 4 + wave;   // grid sized so n < NN always
  const int q = lane >> 4, m = lane & 15;
  const _Float16 rv = rth[(size_t)n * 64 + m * 4 + q];  // channel q*16+m
  const float acc = seg_reduce_fp8(msg, dstbase[n], degi[n], q, m);
  const float r = fmaxf(acc / fmaxf((float)degi[n], 1.0f) + (float)rv, 0.0f);
  xh_out[(size_t)n * 64 + lane] = (_Float16)r;   // lane == channel q*16+m
}

// ----------------------------------------------- pass2 + final GEMM (L1+out)
__global__ __launch_bounds__(256) void pass2_out(
    const unsigned char* __restrict__ msg, const int* __restrict__ dstbase,
    const int* __restrict__ degi, const _Float16* __restrict__ rth,
    const _Float16* __restrict__ xh0, const _Float16* __restrict__ xh1,
    const _Float16* __restrict__ fwT, const float* __restrict__ fb,
    float* __restrict__ out) {
  __shared__ _Float16 sh[16][72];
  const int wave = threadIdx.x >> 6, lane = threadIdx.x & 63;
  const int q = lane >> 4, m = lane & 15;
  const int n0 = blockIdx.x * 16;        // NN % 16 == 0
#pragma unroll 1
  for (int i = 0; i < 4; ++i) {
    const int nl = wave * 4 + i;
    const int n = n0 + nl;
    const _Float16 rv = rth[(size_t)n * 64 + m * 4 + q];
    const float acc = seg_reduce_fp8(msg, dstbase[n], degi[n], q, m);
    const float r = fmaxf(acc / fmaxf((float)degi[n], 1.0f) + (float)rv, 0.0f);
    sh[nl][lane] = (_Float16)r;          // channel q*16+m == lane
  }
  __syncthreads();
  const int g = lane >> 4;
  const int col = wave * 16 + m;
  f16x8 bf[5];
#pragma unroll
  for (int ks = 0; ks < 5; ++ks)
    bf[ks] = *reinterpret_cast<const f16x8*>(fwT + (size_t)col * 160 + ks * 32 + g * 8);
  const int row = n0 + m;
  f16x8 a[5];
  a[0] = *reinterpret_cast<const f16x8*>(xh0 + (size_t)row * 32 + g * 8);
  a[1] = *reinterpret_cast<const f16x8*>(xh1 + (size_t)row * 64 + g * 8);
  a[2] = *reinterpret_cast<const f16x8*>(xh1 + (size_t)row * 64 + 32 + g * 8);
  a[3] = *reinterpret_cast<const f16x8*>(&sh[m][g * 8]);
  a[4] = *reinterpret_cast<const f16x8*>(&sh[m][32 + g * 8]);
  const float fv = fb[col];
  f32x4 acc = (f32x4){fv, fv, fv, fv};
#pragma unroll
  for (int ks = 0; ks < 5; ++ks)
    acc = __builtin_amdgcn_mfma_f32_16x16x32_f16(a[ks], bf[ks], acc, 0, 0, 0);
#pragma unroll
  for (int r = 0; r < 4; ++r)
    out[(size_t)(n0 + g * 4 + r) * 64 + col] = acc[r];
}

// --------------------------------------------------------------- finalize
// (atomic-fallback path only)
template <int IN>
__global__ __launch_bounds__(256) void finalize_kernel(
    const _Float16* __restrict__ xh_in, const float* __restrict__ agg,
    const int* __restrict__ degi, const float* __restrict__ root,
    const float* __restrict__ bias, _Float16* __restrict__ xh_out) {
  __shared__ float rl[IN * 64];
  for (int idx = threadIdx.x; idx < IN * 16; idx += 256)
    reinterpret_cast<float4*>(rl)[idx] = reinterpret_cast<const float4*>(root)[idx];
  __syncthreads();
  const int wave = threadIdx.x >> 6, lane = threadIdx.x & 63;
  const int n = blockIdx.x * 4 + wave;
  if (n >= NN) return;
  const float d = fmaxf((float)degi[n], 1.0f);
  float r = agg[(size_t)n * 64 + lane] / d + bias[lane];
  const _Float16* xr = xh_in + (size_t)n * IN;
#pragma unroll 8
  for (int i = 0; i < IN; ++i) r = fmaf((float)xr[i], rl[i * 64 + lane], r);
  r = fmaxf(r, 0.0f);
  xh_out[(size_t)n * 64 + lane] = (_Float16)r;
}

// ------------------------------------------------------------- output
// (atomic-fallback path only)
__global__ __launch_bounds__(256) void out_mfma(
    const _Float16* __restrict__ xh0, const _Float16* __restrict__ xh1,
    const _Float16* __restrict__ xh2, const _Float16* __restrict__ fwT,
    const float* __restrict__ fb, float* __restrict__ out) {
  const int lane = threadIdx.x & 63, wave = threadIdx.x >> 6;
  const int g = lane >> 4, m = lane & 15;
  const int base = blockIdx.x * 64 + wave * 16;   // NN % 16 == 0
  if (base >= NN) return;
  f16x8 bf[5][4];
#pragma unroll
  for (int ks = 0; ks < 5; ++ks)
#pragma unroll
    for (int nt = 0; nt < 4; ++nt)
      bf[ks][nt] = *reinterpret_cast<const f16x8*>(
          fwT + (size_t)(nt * 16 + m) * 160 + ks * 32 + g * 8);
  const int row = base + m;
  f16x8 a[5];
  a[0] = *reinterpret_cast<const f16x8*>(xh0 + (size_t)row * 32 + g * 8);
  a[1] = *reinterpret_cast<const f16x8*>(xh1 + (size_t)row * 64 + g * 8);
  a[2] = *reinterpret_cast<const f16x8*>(xh1 + (size_t)row * 64 + 32 + g * 8);
  a[3] = *reinterpret_cast<const f16x8*>(xh2 + (size_t)row * 64 + g * 8);
  a[4] = *reinterpret_cast<const f16x8*>(xh2 + (size_t)row * 64 + 32 + g * 8);
  f32x4 acc[4];
#pragma unroll
  for (int nt = 0; nt < 4; ++nt) {
    const float fv = fb[nt * 16 + m];
    acc[nt] = (f32x4){fv, fv, fv, fv};
  }
#pragma unroll
  for (int ks = 0; ks < 5; ++ks)
#pragma unroll
    for (int nt = 0; nt < 4; ++nt)
      acc[nt] = __builtin_amdgcn_mfma_f32_16x16x32_f16(a[ks], bf[ks][nt], acc[nt], 0, 0, 0);
#pragma unroll
  for (int r = 0; r < 4; ++r) {
    float* op = out + (size_t)(base + g * 4 + r) * 64 + m;
#pragma unroll
    for (int nt = 0; nt < 4; ++nt) op[nt * 16] = acc[nt][r];
  }
}

extern "C" void kernel_launch(void* const* d_in, const int* in_sizes, int n_in,
                              void* d_out, int out_size, void* d_ws, size_t ws_size,
                              hipStream_t stream) {
  const float* x0 = (const float*)d_in[0];
  const void* eidx = d_in[1];
  const float* attr = (const float*)d_in[2];
  const float* w0 = (const float*)d_in[3];
  const float* root0 = (const float*)d_in[4];
  const float* b0 = (const float*)d_in[5];
  const float* w1 = (const float*)d_in[6];
  const float* root1 = (const float*)d_in[7];
  const float* b1 = (const float*)d_in[8];
  const float* fw = (const float*)d_in[9];
  const float* fb = (const float*)d_in[10];
  float* out = (float*)d_out;
  (void)in_sizes; (void)n_in; (void)out_size;

  char* wsb = (char*)d_ws;
  size_t off = 0;
  auto alloc = [&](size_t bytes) -> void* {
    void* p = wsb + off;
    off += (bytes + 255) & ~(size_t)255;
    return p;
  };
  int* flag = (int*)alloc(256);
  int* src = (int*)alloc(sizeof(int) * EE);
  int* dst = (int*)alloc(sizeof(int) * EE);
  int* rankE = (int*)alloc(sizeof(int) * EE);
  int2* posrcS = (int2*)alloc(sizeof(int2) * ELIST_LEN);
  f16x4* basS = (f16x4*)alloc(sizeof(f16x4) * ELIST_LEN);
  int* chunkcell = (int*)alloc(sizeof(int) * NBLK_EDGE);
  int* degi = (int*)alloc(sizeof(int) * NN);
  int* dstbase = (int*)alloc(sizeof(int) * NN);
  int* bhT = (int*)alloc(sizeof(int) * EB * 16);
  int* blkbaseT = (int*)alloc(sizeof(int) * EB * 16);
  _Float16* xh0 = (_Float16*)alloc(sizeof(_Float16) * NN * 32);
  _Float16* xh1 = (_Float16*)alloc(sizeof(_Float16) * NN * 64);
  _Float16* xh2 = (_Float16*)alloc(sizeof(_Float16) * NN * 64);  // fallback only
  _Float16* rth = (_Float16*)alloc(sizeof(_Float16) * NN * 64);
  _Float16* wc0 = (_Float16*)alloc(sizeof(_Float16) * 16 * 128 * 64);  // 256KB
  _Float16* wc1 = (_Float16*)alloc(sizeof(_Float16) * 16 * 256 * 64);  // 512KB
  _Float16* fwT = (_Float16*)alloc(sizeof(_Float16) * 64 * 160);
  _Float16* rt0T = (_Float16*)alloc(sizeof(_Float16) * 64 * 32);
  _Float16* rt1T = (_Float16*)alloc(sizeof(_Float16) * 64 * 64);
  const size_t common = off;
  const bool twopass = ws_size >= common + (size_t)EE * 64;  // fp8 msg: 51.2MB
  unsigned char* msg = nullptr;
  float* agg = nullptr;
  if (twopass) msg = (unsigned char*)alloc((size_t)EE * 64);
  else         agg = (float*)alloc(sizeof(float) * (size_t)NN * 64);

  detect_init<<<(NN + 255) / 256, 256, 0, stream>>>(
      (const long long*)eidx, flag, degi);
  prep_conv<<<EB + CONV_BLK, 256, 0, stream>>>(
      eidx, attr, flag, src, dst, rankE, degi, bhT,
      x0, w0, w1, fw, root0, root1, xh0, wc0, wc1, fwT, rt0T, rt1T);
  scan_fused<<<2, 1024, 0, stream>>>(bhT, blkbaseT, chunkcell, posrcS, degi, dstbase);
  scatter_edges<<<EB, 256, 0, stream>>>(attr, blkbaseT, src, dst, rankE, dstbase,
                                        posrcS, basS);

  if (twopass) {
    edge_root<32, true><<<NBLK_EDGE + RT_BLK, 512, 0, stream>>>(
        xh0, wc0, chunkcell, posrcS, basS, rt0T, b0, rth, msg, nullptr);
    pass2_kernel<<<NN / 4, 256, 0, stream>>>(msg, dstbase, degi, rth, xh1);
    edge_root<64, true><<<NBLK_EDGE + RT_BLK, 512, 0, stream>>>(
        xh1, wc1, chunkcell, posrcS, basS, rt1T, b1, rth, msg, nullptr);
    pass2_out<<<NN / 16, 256, 0, stream>>>(msg, dstbase, degi, rth,
                                           xh0, xh1, fwT, fb, out);
  } else {
    hipMemsetAsync(agg, 0, sizeof(float) * NN * 64, stream);
    edge_root<32, false><<<NBLK_EDGE, 512, 0, stream>>>(
        xh0, wc0, chunkcell, posrcS, basS, rt0T, b0, rth, nullptr, agg);
    finalize_kernel<32><<<(NN + 3) / 4, 256, 0, stream>>>(xh0, agg, degi, root0, b0, xh1);
    hipMemsetAsync(agg, 0, sizeof(float) * NN * 64, stream);
    edge_root<64, false><<<NBLK_EDGE, 512, 0, stream>>>(
        xh1, wc1, chunkcell, posrcS, basS, rt1T, b1, rth, nullptr, agg);
    finalize_kernel<64><<<(NN + 3) / 4, 256, 0, stream>>>(xh1, agg, degi, root1, b1, xh2);
    out_mfma<<<(NN + 63) / 64, 256, 0, stream>>>(xh0, xh1, xh2, fwT, fb, out);
  }
}

// Round 19
// 181.709 us; speedup vs baseline: 1.0721x; 1.0721x over previous
//
#include <hip/hip_runtime.h>
#include <hip/hip_bf16.h>
#include <hip/hip_fp16.h>

// SplineCNN forward, MI355X round 19.
// R18 post-mortem: 512-thread edge blocks (8-wave barrier domain) dropped
// occupancy 25->20% and slowed edge_root<64> 42.3->50us - second failure of
// the W-staging-amortization lever (R16: serial rounds -> VGPR blowup; R18:
// wide blocks -> barrier/residency loss). REVERTED VERBATIM to R17, the
// measured best (182.5us): 256-thread edge blocks, 4 waves, W staged per
// 256 edges, pass2_out fusion kept.

typedef __attribute__((ext_vector_type(8))) _Float16 f16x8;
typedef __attribute__((ext_vector_type(4))) _Float16 f16x4;
typedef __attribute__((ext_vector_type(4))) float f32x4;

constexpr int NN = 50000;       // nodes
constexpr int EE = 800000;      // edges
constexpr int CHUNK = 256;      // edges per edge-block (R15/R17 structure)
constexpr int EB = EE / 256;    // 3125 prep/scatter blocks
static_assert(EE % 256 == 0, "prep grid assumes exact divisibility");
constexpr int ELIST_LEN = EE + 16 * CHUNK;
constexpr int NBLK_EDGE = ELIST_LEN / CHUNK;   // 3141
constexpr int RT_BLK = (NN + 63) / 64;         // 782 root-GEMM blocks

// ------------------------------------------------- detect + workspace init
__global__ __launch_bounds__(256) void detect_init(
    const long long* __restrict__ eidx, int* __restrict__ flag,
    int* __restrict__ degi) {
  if (blockIdx.x == 0 && threadIdx.x < 64) {
    long long v = eidx[threadIdx.x];
    bool ok = (v >= 0) && (v < (long long)NN);
    unsigned long long m = __ballot(ok);
    if (threadIdx.x == 0) flag[0] = (m == ~0ull) ? 1 : 0;
  }
  const int i = blockIdx.x * 256 + threadIdx.x;
  if (i < NN) degi[i] = 0;
}

// ------------------------------------------------- prep + one-shot converts
constexpr int F2H_LEN8 = NN * 32 / 8;                 // 200000
constexpr int F2H_BLK = (F2H_LEN8 + 255) / 256;       // 782
constexpr int CW32_BLK = 4 * 16;                      // 64
constexpr int CW64_BLK = 8 * 16;                      // 128
constexpr int CFW_BLK = (64 * 160) / 256;             // 40
constexpr int CRT0_BLK = (64 * 32) / 256;             // 8
constexpr int CRT1_BLK = (64 * 64) / 256;             // 16
constexpr int CONV_BLK = F2H_BLK + CW32_BLK + CW64_BLK + CFW_BLK + CRT0_BLK + CRT1_BLK;

template <int IN>
__device__ __forceinline__ void conv_w_body(
    const float* __restrict__ w, _Float16* __restrict__ wcell, int c, int o) {
  constexpr int K = 4 * IN;
  constexpr int RS = K * 2;
  constexpr int OPR = K / 8;
  const int bx = c & 3, by = c >> 2;
  const int n = o / OPR;
  const int k0 = (o - n * OPR) * 8;
  const int ks = k0 >> 5;
  const int g2 = (k0 & 31) >> 3;
  const int s = (IN == 64) ? (ks & 3) : ks;
  const int i0 = ((IN == 64) ? (ks >> 2) * 32 : 0) + g2 * 8;
  const int kk = (bx + (s & 1)) + 5 * (by + (s >> 1));
  const float* wp = w + ((size_t)kk * IN + i0) * 64 + n;
  f16x8 v;
#pragma unroll
  for (int j = 0; j < 8; ++j) v[j] = (_Float16)wp[(size_t)j * 64];
  const int byte = n * RS + ((k0 * 2) ^ ((n & 15) << 4));
  *reinterpret_cast<f16x8*>(
      reinterpret_cast<char*>(wcell) + (size_t)c * (RS * 64) + byte) = v;
}

__global__ __launch_bounds__(256) void prep_conv(
    const void* __restrict__ eidx, const float* __restrict__ attr,
    const int* __restrict__ flag,
    int* __restrict__ src, int* __restrict__ dst, int* __restrict__ rankE,
    int* __restrict__ degi, int* __restrict__ bhT,
    const float* __restrict__ x0, const float* __restrict__ w0,
    const float* __restrict__ w1, const float* __restrict__ fw,
    const float* __restrict__ root0, const float* __restrict__ root1,
    _Float16* __restrict__ xh0, _Float16* __restrict__ wc0,
    _Float16* __restrict__ wc1, _Float16* __restrict__ fwT,
    _Float16* __restrict__ rt0T, _Float16* __restrict__ rt1T) {
  __shared__ int wc[4][16];
  const int tid = threadIdx.x;
  if (blockIdx.x < EB) {
    const int e = blockIdx.x * 256 + tid;
    int s, d;
    if (flag[0]) {
      s = (int)((const long long*)eidx)[e];
      d = (int)((const long long*)eidx)[EE + e];
    } else {
      s = ((const int*)eidx)[e];
      d = ((const int*)eidx)[EE + e];
    }
    src[e] = s;
    dst[e] = d;
    rankE[e] = atomicAdd(&degi[d], 1);   // rank within dst segment
    const float v0 = attr[2 * e] * 4.0f, v1 = attr[2 * e + 1] * 4.0f;
    const int bx = min(max((int)floorf(v0), 0), 3);
    const int by = min(max((int)floorf(v1), 0), 3);
    const int c = bx + 4 * by;
    const int wave = tid >> 6, lane = tid & 63;
#pragma unroll
    for (int k = 0; k < 16; ++k) {
      unsigned long long mm = __ballot(c == k);
      if (lane == k) wc[wave][k] = __popcll(mm);
    }
    __syncthreads();
    if (tid < 16)
      bhT[tid * EB + blockIdx.x] = wc[0][tid] + wc[1][tid] + wc[2][tid] + wc[3][tid];
    return;
  }
  const int b = blockIdx.x - EB;
  if (b < F2H_BLK) {
    const int i = b * 256 + tid;
    if (i >= F2H_LEN8) return;
    const float4 a = reinterpret_cast<const float4*>(x0)[i * 2];
    const float4 bb = reinterpret_cast<const float4*>(x0)[i * 2 + 1];
    f16x8 v = {(_Float16)a.x, (_Float16)a.y, (_Float16)a.z, (_Float16)a.w,
               (_Float16)bb.x, (_Float16)bb.y, (_Float16)bb.z, (_Float16)bb.w};
    reinterpret_cast<f16x8*>(xh0)[i] = v;
  } else if (b < F2H_BLK + CW32_BLK) {
    const int r = b - F2H_BLK;
    conv_w_body<32>(w0, wc0, r >> 2, (r & 3) * 256 + tid);
  } else if (b < F2H_BLK + CW32_BLK + CW64_BLK) {
    const int r = b - F2H_BLK - CW32_BLK;
    conv_w_body<64>(w1, wc1, r >> 3, (r & 7) * 256 + tid);
  } else if (b < F2H_BLK + CW32_BLK + CW64_BLK + CFW_BLK) {
    const int i = (b - F2H_BLK - CW32_BLK - CW64_BLK) * 256 + tid;  // < 10240
    const int n = i / 160, k = i - n * 160;
    fwT[i] = (_Float16)fw[k * 64 + n];
  } else if (b < F2H_BLK + CW32_BLK + CW64_BLK + CFW_BLK + CRT0_BLK) {
    const int i = (b - F2H_BLK - CW32_BLK - CW64_BLK - CFW_BLK) * 256 + tid;
    const int n = i / 32, k = i - n * 32;   // i < 2048
    rt0T[i] = (_Float16)root0[k * 64 + n];
  } else {
    const int i = (b - F2H_BLK - CW32_BLK - CW64_BLK - CFW_BLK - CRT0_BLK) * 256 + tid;
    const int n = i / 64, k = i - n * 64;   // i < 4096
    rt1T[i] = (_Float16)root1[k * 64 + n];
  }
}

// --------------------------------------------------------------- fused scans
__global__ __launch_bounds__(1024) void scan_fused(
    const int* __restrict__ bhT, int* __restrict__ blkbaseT,
    int* __restrict__ chunkcell, int2* __restrict__ posrcS,
    const int* __restrict__ degi, int* __restrict__ dstbase) {
  const int wave = threadIdx.x >> 6, lane = threadIdx.x & 63;
  if (blockIdx.x == 0) {
    constexpr int CH = (EB + 63) / 64;   // 49
    __shared__ int ofs_s[16];
    __shared__ int tot_s[16];
    int v[CH];
#pragma unroll
    for (int ch = 0; ch < CH; ++ch) {
      const int b = ch * 64 + lane;
      v[ch] = (b < EB) ? bhT[wave * EB + b] : 0;
    }
    {
      int sum = 0;
#pragma unroll
      for (int ch = 0; ch < CH; ++ch) sum += v[ch];
#pragma unroll
      for (int off = 32; off > 0; off >>= 1) sum += __shfl_down(sum, off);
      if (lane == 0) tot_s[wave] = sum;
    }
    __syncthreads();
    if (threadIdx.x == 0) {
      int t = 0;
      for (int c = 0; c < 16; ++c) {
        ofs_s[c] = t;
        t += ((tot_s[c] + CHUNK - 1) / CHUNK) * CHUNK;
      }
    }
    __syncthreads();
    {  // chunk -> cell map; padding chunks get -1
      const int nch = (tot_s[wave] + CHUNK - 1) / CHUNK;
      const int cb = ofs_s[wave] / CHUNK;
      for (int i = lane; i < nch; i += 64) chunkcell[cb + i] = wave;
      if (wave == 15) {
        const int totch = cb + nch;
        for (int i = totch + lane; i < NBLK_EDGE; i += 64) chunkcell[i] = -1;
      }
    }
    {  // pad sentinels for this cell's segment
      const int startp = ofs_s[wave] + tot_s[wave];
      const int endp = ofs_s[wave] + ((tot_s[wave] + CHUNK - 1) / CHUNK) * CHUNK;
      for (int p = startp + lane; p < endp; p += 64) posrcS[p] = make_int2(-1, 0);
    }
    int running = ofs_s[wave];
#pragma unroll
    for (int ch = 0; ch < CH; ++ch) {
      int inc = v[ch];
#pragma unroll
      for (int off = 1; off < 64; off <<= 1) {
        int n = __shfl_up(inc, off);
        if (lane >= off) inc += n;
      }
      const int b = ch * 64 + lane;
      if (b < EB) blkbaseT[wave * EB + b] = running + inc - v[ch];
      running += __shfl(inc, 63);
    }
  } else {
    constexpr int SEG = NN / 16;          // 3125
    constexpr int CH = (SEG + 63) / 64;   // 49
    __shared__ int wofs[16];
    const int nbase = wave * SEG;
    int v[CH];
#pragma unroll
    for (int ch = 0; ch < CH; ++ch) {
      const int i = ch * 64 + lane;
      v[ch] = (i < SEG) ? degi[nbase + i] : 0;
    }
    {
      int sum = 0;
#pragma unroll
      for (int ch = 0; ch < CH; ++ch) sum += v[ch];
#pragma unroll
      for (int off = 32; off > 0; off >>= 1) sum += __shfl_down(sum, off);
      if (lane == 0) wofs[wave] = sum;
    }
    __syncthreads();
    if (threadIdx.x == 0) {
      int t = 0;
      for (int w2 = 0; w2 < 16; ++w2) { int tv = wofs[w2]; wofs[w2] = t; t += tv; }
    }
    __syncthreads();
    int running = wofs[wave];
#pragma unroll
    for (int ch = 0; ch < CH; ++ch) {
      int inc = v[ch];
#pragma unroll
      for (int off = 1; off < 64; off <<= 1) {
        int n = __shfl_up(inc, off);
        if (lane >= off) inc += n;
      }
      const int i = ch * 64 + lane;
      if (i < SEG) dstbase[nbase + i] = running + inc - v[ch];
      running += __shfl(inc, 63);
    }
  }
}

// Deterministic cell-sorted scatter; basis from attr; pos = dstbase + rankE.
__global__ __launch_bounds__(256) void scatter_edges(
    const float* __restrict__ attr, const int* __restrict__ blkbaseT,
    const int* __restrict__ srcArr, const int* __restrict__ dstArr,
    const int* __restrict__ rankE, const int* __restrict__ dstbase,
    int2* __restrict__ posrcS, f16x4* __restrict__ basS) {
  __shared__ int wc[4][16];
  __shared__ int bs[4][16];
  const int tid = threadIdx.x;
  const int e = blockIdx.x * 256 + tid;
  const float v0 = attr[2 * e] * 4.0f, v1 = attr[2 * e + 1] * 4.0f;
  const float fl0 = floorf(v0), fl1 = floorf(v1);
  const float fr0 = v0 - fl0, fr1 = v1 - fl1;
  const int bx = min(max((int)fl0, 0), 3);
  const int by = min(max((int)fl1, 0), 3);
  const int c = bx + 4 * by;
  const f16x4 bq = {(_Float16)((1.0f - fr0) * (1.0f - fr1)),
                    (_Float16)(fr0 * (1.0f - fr1)),
                    (_Float16)((1.0f - fr0) * fr1),
                    (_Float16)(fr0 * fr1)};
  const int wave = tid >> 6, lane = tid & 63;
  int rank = 0;
#pragma unroll
  for (int k = 0; k < 16; ++k) {
    unsigned long long mm = __ballot(c == k);
    if (k == c) rank = __popcll(mm & ((1ull << lane) - 1ull));
    if (lane == k) wc[wave][k] = __popcll(mm);
  }
  const int mypos = dstbase[dstArr[e]] + rankE[e];
  __syncthreads();
  if (tid < 16) {
    int running = blkbaseT[tid * EB + blockIdx.x];
#pragma unroll
    for (int w = 0; w < 4; ++w) { bs[w][tid] = running; running += wc[w][tid]; }
  }
  __syncthreads();
  const int p = bs[wave][c] + rank;
  posrcS[p] = make_int2(srcArr[e], mypos);
  basS[p] = bq;
}

// ------------------------------------------------- edge msg + root GEMM
// R17 structure: 256 edges/block, B read once per (ks,nt) -> 4 MFMAs.
template <int IN, bool TWOPASS>
__global__ __launch_bounds__(256) void edge_root(
    const _Float16* __restrict__ xh, const _Float16* __restrict__ wcell,
    const int* __restrict__ chunkcell,
    const int2* __restrict__ posrcS, const f16x4* __restrict__ basS,
    const _Float16* __restrict__ rootT, const float* __restrict__ bias,
    _Float16* __restrict__ rth,
    unsigned char* __restrict__ msg, float* __restrict__ agg) {
  constexpr int K = 4 * IN;
  constexpr int KSTEPS = K / 32;
  constexpr int RS = K * 2;            // LDS row stride bytes
  constexpr int OPR = K / 8;           // 16B chunks per row
  constexpr int TILES = 4;
  constexpr int NCH = (IN == 64) ? 2 : 1;
  __shared__ f16x8 Wt[64 * OPR];
  const int tid = threadIdx.x;
  const int lane = tid & 63;
  const int wave = tid >> 6;
  const int g = lane >> 4, m = lane & 15;
  if (blockIdx.x >= NBLK_EDGE) {       // ---- root GEMM role ----
    constexpr int KS = IN / 32;
    const int base = (blockIdx.x - NBLK_EDGE) * 64 + wave * 16;
    if (base >= NN) return;
    f16x8 bf[KS][4];
#pragma unroll
    for (int ks = 0; ks < KS; ++ks)
#pragma unroll
      for (int nt = 0; nt < 4; ++nt)
        bf[ks][nt] = *reinterpret_cast<const f16x8*>(
            rootT + (size_t)(nt * 16 + m) * IN + ks * 32 + g * 8);
    const int row = base + m;
    f16x8 a[KS];
#pragma unroll
    for (int ks = 0; ks < KS; ++ks)
      a[ks] = *reinterpret_cast<const f16x8*>(xh + (size_t)row * IN + ks * 32 + g * 8);
    f32x4 acc[4];
#pragma unroll
    for (int nt = 0; nt < 4; ++nt) {
      const float fv = bias[nt * 16 + m];
      acc[nt] = (f32x4){fv, fv, fv, fv};
    }
#pragma unroll
    for (int ks = 0; ks < KS; ++ks)
#pragma unroll
      for (int nt = 0; nt < 4; ++nt)
        acc[nt] = __builtin_amdgcn_mfma_f32_16x16x32_f16(a[ks], bf[ks][nt], acc[nt], 0, 0, 0);
#pragma unroll
    for (int r = 0; r < 4; ++r) {
      const int node = base + g * 4 + r;
      f16x4 pv = {(_Float16)acc[0][r], (_Float16)acc[1][r],
                  (_Float16)acc[2][r], (_Float16)acc[3][r]};
      *reinterpret_cast<f16x4*>(rth + (size_t)node * 64 + m * 4) = pv;
    }
    return;
  }
  // ---- edge transform role ----
  const int c = chunkcell[blockIdx.x];
  if (c < 0) return;                   // fully-padded chunk
  const int base = blockIdx.x * CHUNK;
  const int wbase = base + wave * (CHUNK / 4);
  int2 sp_t[TILES];
  f16x4 bas_t[TILES];
#pragma unroll
  for (int t = 0; t < TILES; ++t) sp_t[t] = posrcS[wbase + t * 16 + m];
#pragma unroll
  for (int t = 0; t < TILES; ++t) bas_t[t] = basS[wbase + t * 16 + m];
  {
    const f16x8* gw = reinterpret_cast<const f16x8*>(wcell) + (size_t)c * (64 * OPR);
    for (int o = tid; o < 64 * OPR; o += 256) Wt[o] = gw[o];
  }
  __syncthreads();
  f16x8 xc[TILES][NCH];
#pragma unroll
  for (int t = 0; t < TILES; ++t) {
    const int row = (sp_t[t].x >= 0) ? sp_t[t].x : 0;
    const f16x8* xr = reinterpret_cast<const f16x8*>(xh + (size_t)row * IN);
    xc[t][0] = xr[g];
    if constexpr (IN == 64) xc[t][1] = xr[4 + g];
  }
  f32x4 acc[TILES][4];
#pragma unroll
  for (int t = 0; t < TILES; ++t)
#pragma unroll
    for (int nt = 0; nt < 4; ++nt) acc[t][nt] = (f32x4){0.f, 0.f, 0.f, 0.f};
#pragma unroll
  for (int ks = 0; ks < KSTEPS; ++ks) {
    const int s = (IN == 64) ? (ks & 3) : ks;
    f16x8 a[TILES];
#pragma unroll
    for (int t = 0; t < TILES; ++t) {
      const f16x8 xin = (IN == 64 && (ks >> 2)) ? xc[t][1] : xc[t][0];
      a[t] = xin * bas_t[t][s];
    }
#pragma unroll
    for (int nt = 0; nt < 4; ++nt) {
      const int n = nt * 16 + m;
      const int byte = n * RS + (((ks * 64) + g * 16) ^ ((n & 15) << 4));
      const f16x8 bfrag = Wt[byte >> 4];   // ONE LDS read -> 4 MFMAs
#pragma unroll
      for (int t = 0; t < TILES; ++t)
        acc[t][nt] = __builtin_amdgcn_mfma_f32_16x16x32_f16(a[t], bfrag, acc[t][nt], 0, 0, 0);
    }
  }
#pragma unroll
  for (int t = 0; t < TILES; ++t) {
#pragma unroll
    for (int r = 0; r < 4; ++r) {
      const int m2 = g * 4 + r;
      const int er = __shfl(sp_t[t].x, m2);
      const int pr = __shfl(sp_t[t].y, m2);
      if (er >= 0) {
        if constexpr (TWOPASS) {
          unsigned int p8 = __builtin_amdgcn_cvt_pk_fp8_f32(acc[t][0][r], acc[t][1][r], 0u, false);
          p8 = __builtin_amdgcn_cvt_pk_fp8_f32(acc[t][2][r], acc[t][3][r], p8, true);
          *reinterpret_cast<unsigned int*>(msg + (size_t)pr * 64 + m * 4) = p8;
        } else {
          float* ap = agg + (size_t)pr * 64 + m;
#pragma unroll
          for (int nt = 0; nt < 4; ++nt) atomicAdd(ap + nt * 16, acc[t][nt][r]);
        }
      }
    }
  }
}

// ------------------------------------------------- pass2 helpers
__device__ __forceinline__ float seg_reduce_fp8(
    const unsigned char* __restrict__ msg, int b0, int dg, int q, int m) {
  const unsigned int* mp =
      reinterpret_cast<const unsigned int*>(msg + (size_t)b0 * 64 + m * 4);
  float a0 = 0.f, a1 = 0.f, a2 = 0.f, a3 = 0.f;
  const int nfull = dg & ~15;
  int j0 = 0;
  for (; j0 < nfull; j0 += 16) {
    const unsigned int* bp = mp + (size_t)j0 * 16;
#pragma unroll
    for (int u = 0; u < 4; ++u) {
      const unsigned int pw = bp[(size_t)(u * 4 + q) * 16];
      const auto lo = __builtin_amdgcn_cvt_pk_f32_fp8(pw, false);
      const auto hi = __builtin_amdgcn_cvt_pk_f32_fp8(pw, true);
      a0 += lo[0]; a1 += lo[1]; a2 += hi[0]; a3 += hi[1];
    }
  }
  if (j0 < dg) {
#pragma unroll
    for (int u = 0; u < 4; ++u) {
      const int jj = j0 + u * 4 + q;
      const int jc = min(jj, dg - 1);
      const unsigned int pw = mp[(size_t)jc * 16];
      const auto lo = __builtin_amdgcn_cvt_pk_f32_fp8(pw, false);
      const auto hi = __builtin_amdgcn_cvt_pk_f32_fp8(pw, true);
      const float wv = (jj < dg) ? 1.0f : 0.0f;
      a0 = fmaf(wv, lo[0], a0);
      a1 = fmaf(wv, lo[1], a1);
      a2 = fmaf(wv, hi[0], a2);
      a3 = fmaf(wv, hi[1], a3);
    }
  }
  a0 += __shfl_xor(a0, 16); a0 += __shfl_xor(a0, 32);
  a1 += __shfl_xor(a1, 16); a1 += __shfl_xor(a1, 32);
  a2 += __shfl_xor(a2, 16); a2 += __shfl_xor(a2, 32);
  a3 += __shfl_xor(a3, 16); a3 += __shfl_xor(a3, 32);
  return (q == 0) ? a0 : (q == 1) ? a1 : (q == 2) ? a2 : a3;
}

// --------------------------------------------------------------- pass2 (L0)
__global__ __launch_bounds__(256) void pass2_kernel(
    const unsigned char* __restrict__ msg, const int* __restrict__ dstbase,
    const int* __restrict__ degi, const _Float16* __restrict__ rth,
    _Float16* __restrict__ xh_out) {
  const int wave = threadIdx.x >> 6, lane = threadIdx.x & 63;
  const int n = blockIdx.x * 4 + wave;   // grid sized so n < NN always
  const int q = lane >> 4, m = lane & 15;
  const _Float16 rv = rth[(size_t)n * 64 + m * 4 + q];  // channel q*16+m
  const float acc = seg_reduce_fp8(msg, dstbase[n], degi[n], q, m);
  const float r = fmaxf(acc / fmaxf((float)degi[n], 1.0f) + (float)rv, 0.0f);
  xh_out[(size_t)n * 64 + lane] = (_Float16)r;   // lane == channel q*16+m
}

// ----------------------------------------------- pass2 + final GEMM (L1+out)
__global__ __launch_bounds__(256) void pass2_out(
    const unsigned char* __restrict__ msg, const int* __restrict__ dstbase,
    const int* __restrict__ degi, const _Float16* __restrict__ rth,
    const _Float16* __restrict__ xh0, const _Float16* __restrict__ xh1,
    const _Float16* __restrict__ fwT, const float* __restrict__ fb,
    float* __restrict__ out) {
  __shared__ _Float16 sh[16][72];
  const int wave = threadIdx.x >> 6, lane = threadIdx.x & 63;
  const int q = lane >> 4, m = lane & 15;
  const int n0 = blockIdx.x * 16;        // NN % 16 == 0
#pragma unroll 1
  for (int i = 0; i < 4; ++i) {
    const int nl = wave * 4 + i;
    const int n = n0 + nl;
    const _Float16 rv = rth[(size_t)n * 64 + m * 4 + q];
    const float acc = seg_reduce_fp8(msg, dstbase[n], degi[n], q, m);
    const float r = fmaxf(acc / fmaxf((float)degi[n], 1.0f) + (float)rv, 0.0f);
    sh[nl][lane] = (_Float16)r;          // channel q*16+m == lane
  }
  __syncthreads();
  const int g = lane >> 4;
  const int col = wave * 16 + m;
  f16x8 bf[5];
#pragma unroll
  for (int ks = 0; ks < 5; ++ks)
    bf[ks] = *reinterpret_cast<const f16x8*>(fwT + (size_t)col * 160 + ks * 32 + g * 8);
  const int row = n0 + m;
  f16x8 a[5];
  a[0] = *reinterpret_cast<const f16x8*>(xh0 + (size_t)row * 32 + g * 8);
  a[1] = *reinterpret_cast<const f16x8*>(xh1 + (size_t)row * 64 + g * 8);
  a[2] = *reinterpret_cast<const f16x8*>(xh1 + (size_t)row * 64 + 32 + g * 8);
  a[3] = *reinterpret_cast<const f16x8*>(&sh[m][g * 8]);
  a[4] = *reinterpret_cast<const f16x8*>(&sh[m][32 + g * 8]);
  const float fv = fb[col];
  f32x4 acc = (f32x4){fv, fv, fv, fv};
#pragma unroll
  for (int ks = 0; ks < 5; ++ks)
    acc = __builtin_amdgcn_mfma_f32_16x16x32_f16(a[ks], bf[ks], acc, 0, 0, 0);
#pragma unroll
  for (int r = 0; r < 4; ++r)
    out[(size_t)(n0 + g * 4 + r) * 64 + col] = acc[r];
}

// --------------------------------------------------------------- finalize
// (atomic-fallback path only)
template <int IN>
__global__ __launch_bounds__(256) void finalize_kernel(
    const _Float16* __restrict__ xh_in, const float* __restrict__ agg,
    const int* __restrict__ degi, const float* __restrict__ root,
    const float* __restrict__ bias, _Float16* __restrict__ xh_out) {
  __shared__ float rl[IN * 64];
  for (int idx = threadIdx.x; idx < IN * 16; idx += 256)
    reinterpret_cast<float4*>(rl)[idx] = reinterpret_cast<const float4*>(root)[idx];
  __syncthreads();
  const int wave = threadIdx.x >> 6, lane = threadIdx.x & 63;
  const int n = blockIdx.x * 4 + wave;
  if (n >= NN) return;
  const float d = fmaxf((float)degi[n], 1.0f);
  float r = agg[(size_t)n * 64 + lane] / d + bias[lane];
  const _Float16* xr = xh_in + (size_t)n * IN;
#pragma unroll 8
  for (int i = 0; i < IN; ++i) r = fmaf((float)xr[i], rl[i * 64 + lane], r);
  r = fmaxf(r, 0.0f);
  xh_out[(size_t)n * 64 + lane] = (_Float16)r;
}

// ------------------------------------------------------------- output
// (atomic-fallback path only)
__global__ __launch_bounds__(256) void out_mfma(
    const _Float16* __restrict__ xh0, const _Float16* __restrict__ xh1,
    const _Float16* __restrict__ xh2, const _Float16* __restrict__ fwT,
    const float* __restrict__ fb, float* __restrict__ out) {
  const int lane = threadIdx.x & 63, wave = threadIdx.x >> 6;
  const int g = lane >> 4, m = lane & 15;
  const int base = blockIdx.x * 64 + wave * 16;   // NN % 16 == 0
  if (base >= NN) return;
  f16x8 bf[5][4];
#pragma unroll
  for (int ks = 0; ks < 5; ++ks)
#pragma unroll
    for (int nt = 0; nt < 4; ++nt)
      bf[ks][nt] = *reinterpret_cast<const f16x8*>(
          fwT + (size_t)(nt * 16 + m) * 160 + ks * 32 + g * 8);
  const int row = base + m;
  f16x8 a[5];
  a[0] = *reinterpret_cast<const f16x8*>(xh0 + (size_t)row * 32 + g * 8);
  a[1] = *reinterpret_cast<const f16x8*>(xh1 + (size_t)row * 64 + g * 8);
  a[2] = *reinterpret_cast<const f16x8*>(xh1 + (size_t)row * 64 + 32 + g * 8);
  a[3] = *reinterpret_cast<const f16x8*>(xh2 + (size_t)row * 64 + g * 8);
  a[4] = *reinterpret_cast<const f16x8*>(xh2 + (size_t)row * 64 + 32 + g * 8);
  f32x4 acc[4];
#pragma unroll
  for (int nt = 0; nt < 4; ++nt) {
    const float fv = fb[nt * 16 + m];
    acc[nt] = (f32x4){fv, fv, fv, fv};
  }
#pragma unroll
  for (int ks = 0; ks < 5; ++ks)
#pragma unroll
    for (int nt = 0; nt < 4; ++nt)
      acc[nt] = __builtin_amdgcn_mfma_f32_16x16x32_f16(a[ks], bf[ks][nt], acc[nt], 0, 0, 0);
#pragma unroll
  for (int r = 0; r < 4; ++r) {
    float* op = out + (size_t)(base + g * 4 + r) * 64 + m;
#pragma unroll
    for (int nt = 0; nt < 4; ++nt) op[nt * 16] = acc[nt][r];
  }
}

extern "C" void kernel_launch(void* const* d_in, const int* in_sizes, int n_in,
                              void* d_out, int out_size, void* d_ws, size_t ws_size,
                              hipStream_t stream) {
  const float* x0 = (const float*)d_in[0];
  const void* eidx = d_in[1];
  const float* attr = (const float*)d_in[2];
  const float* w0 = (const float*)d_in[3];
  const float* root0 = (const float*)d_in[4];
  const float* b0 = (const float*)d_in[5];
  const float* w1 = (const float*)d_in[6];
  const float* root1 = (const float*)d_in[7];
  const float* b1 = (const float*)d_in[8];
  const float* fw = (const float*)d_in[9];
  const float* fb = (const float*)d_in[10];
  float* out = (float*)d_out;
  (void)in_sizes; (void)n_in; (void)out_size;

  char* wsb = (char*)d_ws;
  size_t off = 0;
  auto alloc = [&](size_t bytes) -> void* {
    void* p = wsb + off;
    off += (bytes + 255) & ~(size_t)255;
    return p;
  };
  int* flag = (int*)alloc(256);
  int* src = (int*)alloc(sizeof(int) * EE);
  int* dst = (int*)alloc(sizeof(int) * EE);
  int* rankE = (int*)alloc(sizeof(int) * EE);
  int2* posrcS = (int2*)alloc(sizeof(int2) * ELIST_LEN);
  f16x4* basS = (f16x4*)alloc(sizeof(f16x4) * ELIST_LEN);
  int* chunkcell = (int*)alloc(sizeof(int) * NBLK_EDGE);
  int* degi = (int*)alloc(sizeof(int) * NN);
  int* dstbase = (int*)alloc(sizeof(int) * NN);
  int* bhT = (int*)alloc(sizeof(int) * EB * 16);
  int* blkbaseT = (int*)alloc(sizeof(int) * EB * 16);
  _Float16* xh0 = (_Float16*)alloc(sizeof(_Float16) * NN * 32);
  _Float16* xh1 = (_Float16*)alloc(sizeof(_Float16) * NN * 64);
  _Float16* xh2 = (_Float16*)alloc(sizeof(_Float16) * NN * 64);  // fallback only
  _Float16* rth = (_Float16*)alloc(sizeof(_Float16) * NN * 64);
  _Float16* wc0 = (_Float16*)alloc(sizeof(_Float16) * 16 * 128 * 64);  // 256KB
  _Float16* wc1 = (_Float16*)alloc(sizeof(_Float16) * 16 * 256 * 64);  // 512KB
  _Float16* fwT = (_Float16*)alloc(sizeof(_Float16) * 64 * 160);
  _Float16* rt0T = (_Float16*)alloc(sizeof(_Float16) * 64 * 32);
  _Float16* rt1T = (_Float16*)alloc(sizeof(_Float16) * 64 * 64);
  const size_t common = off;
  const bool twopass = ws_size >= common + (size_t)EE * 64;  // fp8 msg: 51.2MB
  unsigned char* msg = nullptr;
  float* agg = nullptr;
  if (twopass) msg = (unsigned char*)alloc((size_t)EE * 64);
  else         agg = (float*)alloc(sizeof(float) * (size_t)NN * 64);

  detect_init<<<(NN + 255) / 256, 256, 0, stream>>>(
      (const long long*)eidx, flag, degi);
  prep_conv<<<EB + CONV_BLK, 256, 0, stream>>>(
      eidx, attr, flag, src, dst, rankE, degi, bhT,
      x0, w0, w1, fw, root0, root1, xh0, wc0, wc1, fwT, rt0T, rt1T);
  scan_fused<<<2, 1024, 0, stream>>>(bhT, blkbaseT, chunkcell, posrcS, degi, dstbase);
  scatter_edges<<<EB, 256, 0, stream>>>(attr, blkbaseT, src, dst, rankE, dstbase,
                                        posrcS, basS);

  if (twopass) {
    edge_root<32, true><<<NBLK_EDGE + RT_BLK, 256, 0, stream>>>(
        xh0, wc0, chunkcell, posrcS, basS, rt0T, b0, rth, msg, nullptr);
    pass2_kernel<<<NN / 4, 256, 0, stream>>>(msg, dstbase, degi, rth, xh1);
    edge_root<64, true><<<NBLK_EDGE + RT_BLK, 256, 0, stream>>>(
        xh1, wc1, chunkcell, posrcS, basS, rt1T, b1, rth, msg, nullptr);
    pass2_out<<<NN / 16, 256, 0, stream>>>(msg, dstbase, degi, rth,
                                           xh0, xh1, fwT, fb, out);
  } else {
    hipMemsetAsync(agg, 0, sizeof(float) * NN * 64, stream);
    edge_root<32, false><<<NBLK_EDGE, 256, 0, stream>>>(
        xh0, wc0, chunkcell, posrcS, basS, rt0T, b0, rth, nullptr, agg);
    finalize_kernel<32><<<(NN + 3) / 4, 256, 0, stream>>>(xh0, agg, degi, root0, b0, xh1);
    hipMemsetAsync(agg, 0, sizeof(float) * NN * 64, stream);
    edge_root<64, false><<<NBLK_EDGE, 256, 0, stream>>>(
        xh1, wc1, chunkcell, posrcS, basS, rt1T, b1, rth, nullptr, agg);
    finalize_kernel<64><<<(NN + 3) / 4, 256, 0, stream>>>(xh1, agg, degi, root1, b1, xh2);
    out_mfma<<<(NN + 63) / 64, 256, 0, stream>>>(xh0, xh1, xh2, fwT, fb, out);
  }
}